// Round 1
// baseline (2179.828 us; speedup 1.0000x reference)
//
#include <hip/hip_runtime.h>

// B_Cell — B=65536, I=H=256, BD=128. Dtype (bf16 vs f32) detected ON DEVICE
// from h_prev bit patterns; every kernel dual-paths.
// Scratch (f32, lives at the head of the b-region of d_out):
//   [0,65536)        M1        (v^T @ hi for n_r)
//   [65536,131072)   M2        (v^T @ hi for n_t)
//   [131072,131074)  norms     (||n_r||^2, ||n_t||^2)
//   [131076,196612)  MwT       (MwT[c][k] = (1/n2) * sum_j M[k][j]*W_h[c][j])
// b outputs overwrite the scratch region in the final kernel.
//
// Structure (register-tiled f32 GEMMs, 8x4 micro-tile, BK=16 LDS staging):
//   phaseA : hi = tanh(n_h@Wnh^T+bnh) + tanh(h_prev@Wh^T+bh)
//   colred : M  = v^T @ hi                       (128x128 tiles + atomics)
//   mwt    : MwT = (M@Wh^T)^T / n2               (folds projection into GEMM)
//   phaseBC: hi = tanh(v@Wv^T+bv) + tanh(hi@Wh^T - v@MwT + bh)   (in place)
//   phaseC2: b  = tanh(hi@Wbt^T+bbt)

#define B_SZ 65536
#define HDIM 256
#define BDIM 128
#define HI_ELEMS ((size_t)B_SZ * HDIM)       // 16777216
#define SCR_FLOATS (2 * 65536 + 2)           // M1, M2, norms[2] (zeroed)
#define MWT_OFF 131076                        // 16B-aligned f32 offset

typedef unsigned short u16;
typedef unsigned int u32;

__device__ __forceinline__ float blo(u32 u) { return __uint_as_float(u << 16); }
__device__ __forceinline__ float bhi(u32 u) { return __uint_as_float(u & 0xffff0000u); }
__device__ __forceinline__ float b2f(u16 v) { return __uint_as_float(((u32)v) << 16); }
__device__ __forceinline__ u16 f2b(float f) {
    u32 u = __float_as_uint(f);
    return (u16)((u + 0x7fffu + ((u >> 16) & 1u)) >> 16);  // RNE
}

__device__ __forceinline__ int detect_f32_t0(const u16* hp) {
    int sane = 0;
    for (int i = 0; i < 64; ++i) {
        u32 e = (hp[2 * i] >> 7) & 0xFFu;
        sane += (e >= 0x60u && e <= 0x8Fu) ? 1 : 0;
    }
    return (sane < 32) ? 1 : 0;
}

#define DETECT_FLAG(hp)                                                   \
    __shared__ int _sflag;                                                \
    if (threadIdx.x == 0) _sflag = detect_f32_t0((const u16*)(hp));       \
    __syncthreads();                                                      \
    const bool f32m = (_sflag != 0);

__device__ __forceinline__ float ldv(const void* p, size_t i, bool f) {
    return f ? ((const float*)p)[i] : b2f(((const u16*)p)[i]);
}
__device__ __forceinline__ float* scratch_base(void* out, bool f) {
    return (float*)((char*)out + HI_ELEMS * (f ? 4u : 2u));
}
__device__ __forceinline__ void stv4(void* p, size_t i, const float* v, bool f) {
    if (f) {
        *(float4*)((float*)p + i) = make_float4(v[0], v[1], v[2], v[3]);
    } else {
        ushort4 s;
        s.x = f2b(v[0]); s.y = f2b(v[1]); s.z = f2b(v[2]); s.w = f2b(v[3]);
        *(ushort4*)((u16*)p + i) = s;
    }
}

__global__ __launch_bounds__(256) void zero_kernel(const void* hp, void* out) {
    DETECT_FLAG(hp);
    float* scr = scratch_base(out, f32m);
    const int idx = blockIdx.x * 256 + threadIdx.x;
    if (idx < SCR_FLOATS) scr[idx] = 0.f;
}

// ||n_r||^2 -> scr[131072], ||n_t||^2 -> scr[131073] (vectorized loads)
__global__ __launch_bounds__(256) void norms_kernel(const void* hp,
                                                    const void* nr,
                                                    const void* nt,
                                                    void* out) {
    DETECT_FLAG(hp);
    float* scr = scratch_base(out, f32m);
    const size_t total4 = HI_ELEMS / 4;
    const size_t stride = (size_t)gridDim.x * blockDim.x;
    float sr = 0.f, st = 0.f;
    for (size_t i = (size_t)blockIdx.x * blockDim.x + threadIdx.x; i < total4;
         i += stride) {
        if (f32m) {
            float4 a = ((const float4*)nr)[i];
            float4 b = ((const float4*)nt)[i];
            sr = fmaf(a.x, a.x, sr); sr = fmaf(a.y, a.y, sr);
            sr = fmaf(a.z, a.z, sr); sr = fmaf(a.w, a.w, sr);
            st = fmaf(b.x, b.x, st); st = fmaf(b.y, b.y, st);
            st = fmaf(b.z, b.z, st); st = fmaf(b.w, b.w, st);
        } else {
            uint2 a = ((const uint2*)nr)[i];
            uint2 b = ((const uint2*)nt)[i];
            float a0 = blo(a.x), a1 = bhi(a.x), a2 = blo(a.y), a3 = bhi(a.y);
            float b0 = blo(b.x), b1 = bhi(b.x), b2 = blo(b.y), b3 = bhi(b.y);
            sr = fmaf(a0, a0, sr); sr = fmaf(a1, a1, sr);
            sr = fmaf(a2, a2, sr); sr = fmaf(a3, a3, sr);
            st = fmaf(b0, b0, st); st = fmaf(b1, b1, st);
            st = fmaf(b2, b2, st); st = fmaf(b3, b3, st);
        }
    }
    for (int o = 32; o > 0; o >>= 1) {
        sr += __shfl_down(sr, o);
        st += __shfl_down(st, o);
    }
    if ((threadIdx.x & 63) == 0) {
        atomicAdd(&scr[131072], sr);
        atomicAdd(&scr[131073], st);
    }
}

// M{which}[k][c] += sum_r v[r][k]*hi[r][c].  Tiles: 128(k) x 128(c), 512 thr,
// micro 4x8/thread, 16-row LDS chunks, 1024 rows per block, atomic finale.
// grid = dim3(4, 64): x -> (k-tile, c-tile), y -> row chunk.
__global__ __launch_bounds__(512) void colreduce_kernel(const void* hp,
                                                        const void* A,
                                                        void* out, int which) {
    DETECT_FLAG(hp);
    float* M = scratch_base(out, f32m) + (size_t)which * 65536;
    const int k0 = (blockIdx.x >> 1) * 128;
    const int c0 = (blockIdx.x & 1) * 128;
    const size_t r0 = (size_t)blockIdx.y * 1024;
    const int t = threadIdx.x;
    const int tk = t >> 4;   // 0..31 -> k-sub = tk*4
    const int tc = t & 15;   // 0..15 -> c-sub = tc*8

    __shared__ float vS[16][132];
    __shared__ float hS[16][132];

    // staging role: row rr, 8-col segment sg (v for sg<16, hi otherwise)
    const int rr = t >> 5;          // 0..15
    const int sg = t & 31;          // 0..31
    const bool isv = sg < 16;
    const int cw = (isv ? sg : sg - 16) * 8;
    const void* src = isv ? A : (const void*)out;
    const int cg = (isv ? k0 : c0) + cw;
    float* dst = isv ? &vS[rr][cw] : &hS[rr][cw];

    float acc[4][8] = {};
#pragma unroll 1
    for (int rc = 0; rc < 64; ++rc) {
        const size_t r = r0 + (size_t)rc * 16 + rr;
        if (f32m) {
            const float4* p = (const float4*)((const float*)src + (r << 8) + cg);
            float4 q0 = p[0], q1 = p[1];
            dst[0] = q0.x; dst[1] = q0.y; dst[2] = q0.z; dst[3] = q0.w;
            dst[4] = q1.x; dst[5] = q1.y; dst[6] = q1.z; dst[7] = q1.w;
        } else {
            const uint4* p = (const uint4*)((const u16*)src + (r << 8) + cg);
            uint4 q = p[0];
            dst[0] = blo(q.x); dst[1] = bhi(q.x);
            dst[2] = blo(q.y); dst[3] = bhi(q.y);
            dst[4] = blo(q.z); dst[5] = bhi(q.z);
            dst[6] = blo(q.w); dst[7] = bhi(q.w);
        }
        __syncthreads();
#pragma unroll
        for (int j = 0; j < 16; ++j) {
            float4 aq = *(const float4*)&vS[j][tk * 4];
            float4 b0 = *(const float4*)&hS[j][tc * 8];
            float4 b1 = *(const float4*)&hS[j][tc * 8 + 4];
            float a[4] = {aq.x, aq.y, aq.z, aq.w};
            float b[8] = {b0.x, b0.y, b0.z, b0.w, b1.x, b1.y, b1.z, b1.w};
#pragma unroll
            for (int i = 0; i < 4; ++i)
#pragma unroll
                for (int jj = 0; jj < 8; ++jj)
                    acc[i][jj] = fmaf(a[i], b[jj], acc[i][jj]);
        }
        __syncthreads();
    }
#pragma unroll
    for (int i = 0; i < 4; ++i)
#pragma unroll
        for (int j = 0; j < 8; ++j)
            atomicAdd(&M[(size_t)(k0 + tk * 4 + i) * 256 + (c0 + tc * 8 + j)],
                      acc[i][j]);
}

// MwT[c][k] = (1/n2) * dot(M row k, W_h row c).  grid 256 (c) x 256 thr (k).
__global__ __launch_bounds__(256) void build_mwt_kernel(const void* hp,
                                                        const void* Wh,
                                                        void* out, int which) {
    DETECT_FLAG(hp);
    float* scr = scratch_base(out, f32m);
    const float* M = scr + (size_t)which * 65536;
    const float n2 = scr[131072 + which];
    const float inv = (n2 > 1e-30f) ? 1.0f / n2 : 0.f;
    float* MwT = scr + MWT_OFF;
    const int c = blockIdx.x, k = threadIdx.x;
    __shared__ float sw[256];
    sw[k] = ldv(Wh, ((size_t)c << 8) + k, f32m);
    __syncthreads();
    const float4* mp = (const float4*)(M + ((size_t)k << 8));
    float acc = 0.f;
#pragma unroll 8
    for (int j = 0; j < 64; ++j) {
        float4 q = mp[j];
        const float* w = &sw[j * 4];
        acc = fmaf(q.x, w[0], acc);
        acc = fmaf(q.y, w[1], acc);
        acc = fmaf(q.z, w[2], acc);
        acc = fmaf(q.w, w[3], acc);
    }
    MwT[((size_t)c << 8) + k] = inv * acc;
}

// Fused register-tiled GEMM. Block tile: 32 rows x BN cols, BK=16, BN threads,
// thread micro-tile 8x4 (ty = t/(BN/4) in 0..3 -> rows, tx -> 4 cols).
// MODE 0 (phaseA):  out = tanh(A0@B0^T+b0) + tanh(A1@B1^T+b1)      BN=256
// MODE 1 (phaseBC): out = tanh(A0@B0^T+b0) + tanh(A1@B1^T - A0@MwT + b1), in place
// MODE 2 (phaseC2): out_b = tanh(A0@B0^T+b0)                        BN=128
template <int MODE>
__global__ __launch_bounds__((MODE == 2) ? 128 : 256) void gemm_fused(
    const void* hp, const void* A0p, const void* A1p, const void* B0p,
    const void* B1p, const void* bias0, const void* bias1, void* out) {
    constexpr int NA = (MODE == 2) ? 1 : 2;
    constexpr int NB = (MODE == 0) ? 2 : ((MODE == 1) ? 3 : 1);
    constexpr int BN = (MODE == 2) ? 128 : 256;
    constexpr int TX = BN / 4;

    DETECT_FLAG(hp);
    const float* MwT =
        (MODE == 1) ? (scratch_base(out, f32m) + MWT_OFF) : (const float*)nullptr;

    __shared__ float As[NA][16][36];   // [mat][k][m], pad 4 (16B-aligned rows)
    __shared__ float Bs[NB][16][BN];   // [mat][k][n]

    const int t = threadIdx.x;
    const int tx = t % TX;
    const int ty = t / TX;
    const int m0 = blockIdx.x * 32;

    // staging roles (A): m-row + (matrix, k-quarter)
    const int sm = t & 31;
    const int sgp = t >> 5;            // BN=256: 0..7 ; BN=128: 0..3
    const int smat = sgp >> 2;         // 0..NA-1
    const int sk4 = (sgp & 3) * 4;

    float acc[NB][8][4] = {};

#pragma unroll 1
    for (int kc = 0; kc < 16; ++kc) {
        const int k0 = kc * 16;
        // ---- stage B tiles: thread stages row n = t of each B matrix
        {
            const int n = t;
#pragma unroll
            for (int b = 0; b < NB; ++b) {
                const void* W = (b == 0) ? B0p : ((b == 1) ? B1p : (const void*)MwT);
                const bool bf32 = f32m || (b == 2);  // MwT is always f32
                float* d = &Bs[b][0][n];
                if (bf32) {
                    const float4* p =
                        (const float4*)((const float*)W + ((size_t)n << 8) + k0);
                    float4 q0 = p[0], q1 = p[1], q2 = p[2], q3 = p[3];
                    d[0 * BN] = q0.x; d[1 * BN] = q0.y; d[2 * BN] = q0.z; d[3 * BN] = q0.w;
                    d[4 * BN] = q1.x; d[5 * BN] = q1.y; d[6 * BN] = q1.z; d[7 * BN] = q1.w;
                    d[8 * BN] = q2.x; d[9 * BN] = q2.y; d[10 * BN] = q2.z; d[11 * BN] = q2.w;
                    d[12 * BN] = q3.x; d[13 * BN] = q3.y; d[14 * BN] = q3.z; d[15 * BN] = q3.w;
                } else {
                    const uint4* p =
                        (const uint4*)((const u16*)W + ((size_t)n << 8) + k0);
                    uint4 q0 = p[0], q1 = p[1];
                    d[0 * BN] = blo(q0.x); d[1 * BN] = bhi(q0.x);
                    d[2 * BN] = blo(q0.y); d[3 * BN] = bhi(q0.y);
                    d[4 * BN] = blo(q0.z); d[5 * BN] = bhi(q0.z);
                    d[6 * BN] = blo(q0.w); d[7 * BN] = bhi(q0.w);
                    d[8 * BN] = blo(q1.x); d[9 * BN] = bhi(q1.x);
                    d[10 * BN] = blo(q1.y); d[11 * BN] = bhi(q1.y);
                    d[12 * BN] = blo(q1.z); d[13 * BN] = bhi(q1.z);
                    d[14 * BN] = blo(q1.w); d[15 * BN] = bhi(q1.w);
                }
            }
        }
        // ---- stage A tiles (transposed into LDS): 4 k-values of one row
        {
            const void* A = (smat == 0) ? A0p : A1p;
            const size_t off = ((size_t)(m0 + sm) << 8) + k0 + sk4;
            if (f32m) {
                float4 q = *(const float4*)((const float*)A + off);
                As[smat][sk4 + 0][sm] = q.x;
                As[smat][sk4 + 1][sm] = q.y;
                As[smat][sk4 + 2][sm] = q.z;
                As[smat][sk4 + 3][sm] = q.w;
            } else {
                const u32* p = (const u32*)((const u16*)A + off);
                u32 q0 = p[0], q1 = p[1];
                As[smat][sk4 + 0][sm] = blo(q0);
                As[smat][sk4 + 1][sm] = bhi(q0);
                As[smat][sk4 + 2][sm] = blo(q1);
                As[smat][sk4 + 3][sm] = bhi(q1);
            }
        }
        __syncthreads();
        // ---- compute: 16 k-steps, 8x4 micro-tile per product
#pragma unroll
        for (int k = 0; k < 16; ++k) {
            float a0[8], a1[8];
            {
                float4 u = *(const float4*)&As[0][k][ty * 8];
                float4 v = *(const float4*)&As[0][k][ty * 8 + 4];
                a0[0] = u.x; a0[1] = u.y; a0[2] = u.z; a0[3] = u.w;
                a0[4] = v.x; a0[5] = v.y; a0[6] = v.z; a0[7] = v.w;
            }
            if constexpr (NA == 2) {
                float4 u = *(const float4*)&As[1][k][ty * 8];
                float4 v = *(const float4*)&As[1][k][ty * 8 + 4];
                a1[0] = u.x; a1[1] = u.y; a1[2] = u.z; a1[3] = u.w;
                a1[4] = v.x; a1[5] = v.y; a1[6] = v.z; a1[7] = v.w;
            }
            float b0[4], b1[4], b2[4];
            {
                float4 u = *(const float4*)&Bs[0][k][tx * 4];
                b0[0] = u.x; b0[1] = u.y; b0[2] = u.z; b0[3] = u.w;
            }
            if constexpr (NB >= 2) {
                float4 u = *(const float4*)&Bs[1][k][tx * 4];
                b1[0] = u.x; b1[1] = u.y; b1[2] = u.z; b1[3] = u.w;
            }
            if constexpr (NB == 3) {
                float4 u = *(const float4*)&Bs[2][k][tx * 4];
                b2[0] = u.x; b2[1] = u.y; b2[2] = u.z; b2[3] = u.w;
            }
#pragma unroll
            for (int i = 0; i < 8; ++i)
#pragma unroll
                for (int j = 0; j < 4; ++j) {
                    acc[0][i][j] = fmaf(a0[i], b0[j], acc[0][i][j]);
                    if constexpr (NB >= 2)
                        acc[1][i][j] = fmaf(a1[i], b1[j], acc[1][i][j]);
                    if constexpr (NB == 3)
                        acc[2][i][j] = fmaf(a0[i], b2[j], acc[2][i][j]);
                }
        }
        __syncthreads();
    }

    // ---- epilogue
    float b0v[4], b1v[4];
#pragma unroll
    for (int j = 0; j < 4; ++j) {
        b0v[j] = ldv(bias0, tx * 4 + j, f32m);
        if constexpr (MODE != 2) b1v[j] = ldv(bias1, tx * 4 + j, f32m);
    }
#pragma unroll
    for (int i = 0; i < 8; ++i) {
        const size_t r = (size_t)m0 + ty * 8 + i;
        float vo[4];
#pragma unroll
        for (int j = 0; j < 4; ++j) {
            if constexpr (MODE == 0)
                vo[j] = tanhf(acc[0][i][j] + b0v[j]) + tanhf(acc[1][i][j] + b1v[j]);
            else if constexpr (MODE == 1)
                vo[j] = tanhf(acc[0][i][j] + b0v[j]) +
                        tanhf(acc[1][i][j] - acc[2][i][j] + b1v[j]);
            else
                vo[j] = tanhf(acc[0][i][j] + b0v[j]);
        }
        if constexpr (MODE == 2)
            stv4(out, HI_ELEMS + r * BDIM + tx * 4, vo, f32m);
        else
            stv4(out, (r << 8) + tx * 4, vo, f32m);
    }
}

extern "C" void kernel_launch(void* const* d_in, const int* in_sizes, int n_in,
                              void* d_out, int out_size, void* d_ws, size_t ws_size,
                              hipStream_t stream) {
    (void)in_sizes; (void)n_in; (void)out_size; (void)d_ws; (void)ws_size;
    const void* h_prev = d_in[0];
    const void* n_h  = d_in[1];
    const void* n_r  = d_in[2];
    const void* n_t  = d_in[3];
    const void* W_nh = d_in[4];
    const void* b_nh = d_in[5];
    const void* W_nr = d_in[6];
    const void* b_nr = d_in[7];
    const void* W_nt = d_in[8];
    const void* b_nt = d_in[9];
    const void* W_bt = d_in[10];
    const void* b_bt = d_in[11];
    const void* W_h  = d_in[12];
    const void* b_h  = d_in[13];

    zero_kernel<<<(SCR_FLOATS + 255) / 256, 256, 0, stream>>>(h_prev, d_out);
    norms_kernel<<<2048, 256, 0, stream>>>(h_prev, n_r, n_t, d_out);
    gemm_fused<0><<<B_SZ / 32, 256, 0, stream>>>(h_prev, n_h, h_prev, W_nh, W_h,
                                                 b_nh, b_h, d_out);
    colreduce_kernel<<<dim3(4, 64), 512, 0, stream>>>(h_prev, n_r, d_out, 0);
    build_mwt_kernel<<<256, 256, 0, stream>>>(h_prev, W_h, d_out, 0);
    gemm_fused<1><<<B_SZ / 32, 256, 0, stream>>>(h_prev, n_r, d_out, W_nr, W_h,
                                                 b_nr, b_h, d_out);
    colreduce_kernel<<<dim3(4, 64), 512, 0, stream>>>(h_prev, n_t, d_out, 1);
    build_mwt_kernel<<<256, 256, 0, stream>>>(h_prev, W_h, d_out, 1);
    gemm_fused<1><<<B_SZ / 32, 256, 0, stream>>>(h_prev, n_t, d_out, W_nt, W_h,
                                                 b_nt, b_h, d_out);
    gemm_fused<2><<<B_SZ / 32, 128, 0, stream>>>(h_prev, d_out, nullptr, W_bt,
                                                 nullptr, b_bt, nullptr, d_out);
}

// Round 4
// 1888.668 us; speedup vs baseline: 1.1542x; 1.1542x over previous
//
#include <hip/hip_runtime.h>

// B_Cell — B=65536, I=H=256, BD=128. Dtype (bf16 vs f32) detected ON DEVICE.
// R4: fix R3's inter-block race: gemm_mfma<1> read s2 planes (full K) while
// writing new planes into s2. Now plane slots ping-pong: gemm<0>->s2,
// gemm<1>#1 reads s2 writes s1, gemm<1>#2 reads s1 writes s2, gemm<2> reads s2.
// f32-VALU fallback path retained for small ws_size.
//
// d_out scratch (f32, head of b-region):
//   [0,65536) M1 | [65536,131072) M2 | [131072,131074) norms | [131076,...) MwT(f32, fallback only)
// d_ws (MFMA path only, ws_size >= WS_NEED):
//   slot0/1/2: activation plane pairs (h,l), each plane 16777216 bf16 = 33.5MB
//   weight plane pairs at WWPL: Wnh, Wh, Wnr, Wnt, Wbt, MwT(negated)

#define B_SZ 65536
#define HDIM 256
#define BDIM 128
#define HI_ELEMS ((size_t)B_SZ * HDIM)       // 16777216
#define SCR_FLOATS (2 * 65536 + 2)
#define MWT_OFF 131076

#define WSLOT_B (2ull * HI_ELEMS)            // bytes per bf16 plane = 33554432
#define WWPL (6ull * WSLOT_B)                // 201326592: weight planes base
#define WS_NEED (WWPL + 6ull * 262144ull)    // 202899456

typedef unsigned short u16;
typedef unsigned int u32;
typedef __attribute__((ext_vector_type(8))) short bf16x8;
typedef __attribute__((ext_vector_type(4))) float f32x4;

__device__ __forceinline__ float blo(u32 u) { return __uint_as_float(u << 16); }
__device__ __forceinline__ float bhi(u32 u) { return __uint_as_float(u & 0xffff0000u); }
__device__ __forceinline__ float b2f(u16 v) { return __uint_as_float(((u32)v) << 16); }
__device__ __forceinline__ u16 f2b(float f) {
    u32 u = __float_as_uint(f);
    return (u16)((u + 0x7fffu + ((u >> 16) & 1u)) >> 16);  // RNE
}

__device__ __forceinline__ int detect_f32_t0(const u16* hp) {
    int sane = 0;
    for (int i = 0; i < 64; ++i) {
        u32 e = (hp[2 * i] >> 7) & 0xFFu;
        sane += (e >= 0x60u && e <= 0x8Fu) ? 1 : 0;
    }
    return (sane < 32) ? 1 : 0;
}

#define DETECT_FLAG(hp)                                                   \
    __shared__ int _sflag;                                                \
    if (threadIdx.x == 0) _sflag = detect_f32_t0((const u16*)(hp));       \
    __syncthreads();                                                      \
    const bool f32m = (_sflag != 0);

__device__ __forceinline__ float ldv(const void* p, size_t i, bool f) {
    return f ? ((const float*)p)[i] : b2f(((const u16*)p)[i]);
}
__device__ __forceinline__ void stv(void* p, size_t i, float v, bool f) {
    if (f) ((float*)p)[i] = v;
    else   ((u16*)p)[i] = f2b(v);
}
__device__ __forceinline__ float* scratch_base(void* out, bool f) {
    return (float*)((char*)out + HI_ELEMS * (f ? 4u : 2u));
}
__device__ __forceinline__ void stv4(void* p, size_t i, const float* v, bool f) {
    if (f) {
        *(float4*)((float*)p + i) = make_float4(v[0], v[1], v[2], v[3]);
    } else {
        ushort4 s;
        s.x = f2b(v[0]); s.y = f2b(v[1]); s.z = f2b(v[2]); s.w = f2b(v[3]);
        *(ushort4*)((u16*)p + i) = s;
    }
}

__global__ __launch_bounds__(256) void zero_kernel(const void* hp, void* out) {
    DETECT_FLAG(hp);
    float* scr = scratch_base(out, f32m);
    const int idx = blockIdx.x * 256 + threadIdx.x;
    if (idx < SCR_FLOATS) scr[idx] = 0.f;
}

__global__ __launch_bounds__(256) void norms_kernel(const void* hp,
                                                    const void* nr,
                                                    const void* nt,
                                                    void* out) {
    DETECT_FLAG(hp);
    float* scr = scratch_base(out, f32m);
    const size_t total4 = HI_ELEMS / 4;
    const size_t stride = (size_t)gridDim.x * blockDim.x;
    float sr = 0.f, st = 0.f;
    for (size_t i = (size_t)blockIdx.x * blockDim.x + threadIdx.x; i < total4;
         i += stride) {
        if (f32m) {
            float4 a = ((const float4*)nr)[i];
            float4 b = ((const float4*)nt)[i];
            sr = fmaf(a.x, a.x, sr); sr = fmaf(a.y, a.y, sr);
            sr = fmaf(a.z, a.z, sr); sr = fmaf(a.w, a.w, sr);
            st = fmaf(b.x, b.x, st); st = fmaf(b.y, b.y, st);
            st = fmaf(b.z, b.z, st); st = fmaf(b.w, b.w, st);
        } else {
            uint2 a = ((const uint2*)nr)[i];
            uint2 b = ((const uint2*)nt)[i];
            float a0 = blo(a.x), a1 = bhi(a.x), a2 = blo(a.y), a3 = bhi(a.y);
            float b0 = blo(b.x), b1 = bhi(b.x), b2 = blo(b.y), b3 = bhi(b.y);
            sr = fmaf(a0, a0, sr); sr = fmaf(a1, a1, sr);
            sr = fmaf(a2, a2, sr); sr = fmaf(a3, a3, sr);
            st = fmaf(b0, b0, st); st = fmaf(b1, b1, st);
            st = fmaf(b2, b2, st); st = fmaf(b3, b3, st);
        }
    }
    for (int o = 32; o > 0; o >>= 1) {
        sr += __shfl_down(sr, o);
        st += __shfl_down(st, o);
    }
    if ((threadIdx.x & 63) == 0) {
        atomicAdd(&scr[131072], sr);
        atomicAdd(&scr[131073], st);
    }
}

// M{which}[k][c] += sum_r v[r][k]*hi[r][c].
__global__ __launch_bounds__(512) void colreduce_kernel(const void* hp,
                                                        const void* A,
                                                        void* out, int which) {
    DETECT_FLAG(hp);
    float* M = scratch_base(out, f32m) + (size_t)which * 65536;
    const int k0 = (blockIdx.x >> 1) * 128;
    const int c0 = (blockIdx.x & 1) * 128;
    const size_t r0 = (size_t)blockIdx.y * 1024;
    const int t = threadIdx.x;
    const int tk = t >> 4;
    const int tc = t & 15;

    __shared__ float vS[16][132];
    __shared__ float hS[16][132];

    const int rr = t >> 5;
    const int sg = t & 31;
    const bool isv = sg < 16;
    const int cw = (isv ? sg : sg - 16) * 8;
    const void* src = isv ? A : (const void*)out;
    const int cg = (isv ? k0 : c0) + cw;
    float* dst = isv ? &vS[rr][cw] : &hS[rr][cw];

    float acc[4][8] = {};
#pragma unroll 1
    for (int rc = 0; rc < 64; ++rc) {
        const size_t r = r0 + (size_t)rc * 16 + rr;
        if (f32m) {
            const float4* p = (const float4*)((const float*)src + (r << 8) + cg);
            float4 q0 = p[0], q1 = p[1];
            dst[0] = q0.x; dst[1] = q0.y; dst[2] = q0.z; dst[3] = q0.w;
            dst[4] = q1.x; dst[5] = q1.y; dst[6] = q1.z; dst[7] = q1.w;
        } else {
            const uint4* p = (const uint4*)((const u16*)src + (r << 8) + cg);
            uint4 q = p[0];
            dst[0] = blo(q.x); dst[1] = bhi(q.x);
            dst[2] = blo(q.y); dst[3] = bhi(q.y);
            dst[4] = blo(q.z); dst[5] = bhi(q.z);
            dst[6] = blo(q.w); dst[7] = bhi(q.w);
        }
        __syncthreads();
#pragma unroll
        for (int j = 0; j < 16; ++j) {
            float4 aq = *(const float4*)&vS[j][tk * 4];
            float4 b0 = *(const float4*)&hS[j][tc * 8];
            float4 b1 = *(const float4*)&hS[j][tc * 8 + 4];
            float a[4] = {aq.x, aq.y, aq.z, aq.w};
            float b[8] = {b0.x, b0.y, b0.z, b0.w, b1.x, b1.y, b1.z, b1.w};
#pragma unroll
            for (int i = 0; i < 4; ++i)
#pragma unroll
                for (int jj = 0; jj < 8; ++jj)
                    acc[i][jj] = fmaf(a[i], b[jj], acc[i][jj]);
        }
        __syncthreads();
    }
#pragma unroll
    for (int i = 0; i < 4; ++i)
#pragma unroll
        for (int j = 0; j < 8; ++j)
            atomicAdd(&M[(size_t)(k0 + tk * 4 + i) * 256 + (c0 + tc * 8 + j)],
                      acc[i][j]);
}

// ---------- fallback (f32 VALU) path: build_mwt + gemm_fused ----------

__global__ __launch_bounds__(256) void build_mwt_kernel(const void* hp,
                                                        const void* Wh,
                                                        void* out, int which) {
    DETECT_FLAG(hp);
    float* scr = scratch_base(out, f32m);
    const float* M = scr + (size_t)which * 65536;
    const float n2 = scr[131072 + which];
    const float inv = (n2 > 1e-30f) ? 1.0f / n2 : 0.f;
    float* MwT = scr + MWT_OFF;
    const int c = blockIdx.x, k = threadIdx.x;
    __shared__ float sw[256];
    sw[k] = ldv(Wh, ((size_t)c << 8) + k, f32m);
    __syncthreads();
    const float4* mp = (const float4*)(M + ((size_t)k << 8));
    float acc = 0.f;
#pragma unroll 8
    for (int j = 0; j < 64; ++j) {
        float4 q = mp[j];
        const float* w = &sw[j * 4];
        acc = fmaf(q.x, w[0], acc);
        acc = fmaf(q.y, w[1], acc);
        acc = fmaf(q.z, w[2], acc);
        acc = fmaf(q.w, w[3], acc);
    }
    MwT[((size_t)c << 8) + k] = inv * acc;
}

template <int MODE>
__global__ __launch_bounds__((MODE == 2) ? 128 : 256) void gemm_fused(
    const void* hp, const void* A0p, const void* A1p, const void* B0p,
    const void* B1p, const void* bias0, const void* bias1, void* out) {
    constexpr int NA = (MODE == 2) ? 1 : 2;
    constexpr int NB = (MODE == 0) ? 2 : ((MODE == 1) ? 3 : 1);
    constexpr int BN = (MODE == 2) ? 128 : 256;
    constexpr int TX = BN / 4;

    DETECT_FLAG(hp);
    const float* MwT =
        (MODE == 1) ? (scratch_base(out, f32m) + MWT_OFF) : (const float*)nullptr;

    __shared__ float As[NA][16][36];
    __shared__ float Bs[NB][16][BN];

    const int t = threadIdx.x;
    const int tx = t % TX;
    const int ty = t / TX;
    const int m0 = blockIdx.x * 32;

    const int sm = t & 31;
    const int sgp = t >> 5;
    const int smat = sgp >> 2;
    const int sk4 = (sgp & 3) * 4;

    float acc[NB][8][4] = {};

#pragma unroll 1
    for (int kc = 0; kc < 16; ++kc) {
        const int k0 = kc * 16;
        {
            const int n = t;
#pragma unroll
            for (int b = 0; b < NB; ++b) {
                const void* W = (b == 0) ? B0p : ((b == 1) ? B1p : (const void*)MwT);
                const bool bf32 = f32m || (b == 2);
                float* d = &Bs[b][0][n];
                if (bf32) {
                    const float4* p =
                        (const float4*)((const float*)W + ((size_t)n << 8) + k0);
                    float4 q0 = p[0], q1 = p[1], q2 = p[2], q3 = p[3];
                    d[0 * BN] = q0.x; d[1 * BN] = q0.y; d[2 * BN] = q0.z; d[3 * BN] = q0.w;
                    d[4 * BN] = q1.x; d[5 * BN] = q1.y; d[6 * BN] = q1.z; d[7 * BN] = q1.w;
                    d[8 * BN] = q2.x; d[9 * BN] = q2.y; d[10 * BN] = q2.z; d[11 * BN] = q2.w;
                    d[12 * BN] = q3.x; d[13 * BN] = q3.y; d[14 * BN] = q3.z; d[15 * BN] = q3.w;
                } else {
                    const uint4* p =
                        (const uint4*)((const u16*)W + ((size_t)n << 8) + k0);
                    uint4 q0 = p[0], q1 = p[1];
                    d[0 * BN] = blo(q0.x); d[1 * BN] = bhi(q0.x);
                    d[2 * BN] = blo(q0.y); d[3 * BN] = bhi(q0.y);
                    d[4 * BN] = blo(q0.z); d[5 * BN] = bhi(q0.z);
                    d[6 * BN] = blo(q0.w); d[7 * BN] = bhi(q0.w);
                    d[8 * BN] = blo(q1.x); d[9 * BN] = bhi(q1.x);
                    d[10 * BN] = blo(q1.y); d[11 * BN] = bhi(q1.y);
                    d[12 * BN] = blo(q1.z); d[13 * BN] = bhi(q1.z);
                    d[14 * BN] = blo(q1.w); d[15 * BN] = bhi(q1.w);
                }
            }
        }
        {
            const void* A = (smat == 0) ? A0p : A1p;
            const size_t off = ((size_t)(m0 + sm) << 8) + k0 + sk4;
            if (f32m) {
                float4 q = *(const float4*)((const float*)A + off);
                As[smat][sk4 + 0][sm] = q.x;
                As[smat][sk4 + 1][sm] = q.y;
                As[smat][sk4 + 2][sm] = q.z;
                As[smat][sk4 + 3][sm] = q.w;
            } else {
                const u32* p = (const u32*)((const u16*)A + off);
                u32 q0 = p[0], q1 = p[1];
                As[smat][sk4 + 0][sm] = blo(q0);
                As[smat][sk4 + 1][sm] = bhi(q0);
                As[smat][sk4 + 2][sm] = blo(q1);
                As[smat][sk4 + 3][sm] = bhi(q1);
            }
        }
        __syncthreads();
#pragma unroll
        for (int k = 0; k < 16; ++k) {
            float a0[8], a1[8];
            {
                float4 u = *(const float4*)&As[0][k][ty * 8];
                float4 v = *(const float4*)&As[0][k][ty * 8 + 4];
                a0[0] = u.x; a0[1] = u.y; a0[2] = u.z; a0[3] = u.w;
                a0[4] = v.x; a0[5] = v.y; a0[6] = v.z; a0[7] = v.w;
            }
            if constexpr (NA == 2) {
                float4 u = *(const float4*)&As[1][k][ty * 8];
                float4 v = *(const float4*)&As[1][k][ty * 8 + 4];
                a1[0] = u.x; a1[1] = u.y; a1[2] = u.z; a1[3] = u.w;
                a1[4] = v.x; a1[5] = v.y; a1[6] = v.z; a1[7] = v.w;
            }
            float b0[4], b1[4], b2[4];
            {
                float4 u = *(const float4*)&Bs[0][k][tx * 4];
                b0[0] = u.x; b0[1] = u.y; b0[2] = u.z; b0[3] = u.w;
            }
            if constexpr (NB >= 2) {
                float4 u = *(const float4*)&Bs[1][k][tx * 4];
                b1[0] = u.x; b1[1] = u.y; b1[2] = u.z; b1[3] = u.w;
            }
            if constexpr (NB == 3) {
                float4 u = *(const float4*)&Bs[2][k][tx * 4];
                b2[0] = u.x; b2[1] = u.y; b2[2] = u.z; b2[3] = u.w;
            }
#pragma unroll
            for (int i = 0; i < 8; ++i)
#pragma unroll
                for (int j = 0; j < 4; ++j) {
                    acc[0][i][j] = fmaf(a0[i], b0[j], acc[0][i][j]);
                    if constexpr (NB >= 2)
                        acc[1][i][j] = fmaf(a1[i], b1[j], acc[1][i][j]);
                    if constexpr (NB == 3)
                        acc[2][i][j] = fmaf(a0[i], b2[j], acc[2][i][j]);
                }
        }
        __syncthreads();
    }

    float b0v[4], b1v[4];
#pragma unroll
    for (int j = 0; j < 4; ++j) {
        b0v[j] = ldv(bias0, tx * 4 + j, f32m);
        if constexpr (MODE != 2) b1v[j] = ldv(bias1, tx * 4 + j, f32m);
    }
#pragma unroll
    for (int i = 0; i < 8; ++i) {
        const size_t r = (size_t)m0 + ty * 8 + i;
        float vo[4];
#pragma unroll
        for (int j = 0; j < 4; ++j) {
            if constexpr (MODE == 0)
                vo[j] = tanhf(acc[0][i][j] + b0v[j]) + tanhf(acc[1][i][j] + b1v[j]);
            else if constexpr (MODE == 1)
                vo[j] = tanhf(acc[0][i][j] + b0v[j]) +
                        tanhf(acc[1][i][j] - acc[2][i][j] + b1v[j]);
            else
                vo[j] = tanhf(acc[0][i][j] + b0v[j]);
        }
        if constexpr (MODE == 2)
            stv4(out, HI_ELEMS + r * BDIM + tx * 4, vo, f32m);
        else
            stv4(out, (r << 8) + tx * 4, vo, f32m);
    }
}

// ---------- MFMA (bf16x3) path ----------

// Split src (f32 or bf16, n elems) into bf16 hi/lo planes.
__global__ __launch_bounds__(256) void split_kernel(const void* hp,
                                                    const void* src,
                                                    u16* dh, u16* dl, size_t n) {
    DETECT_FLAG(hp);
    const size_t n4 = n / 4;
    const size_t stride = (size_t)gridDim.x * blockDim.x;
    for (size_t i = (size_t)blockIdx.x * blockDim.x + threadIdx.x; i < n4;
         i += stride) {
        ushort4 h, l;
        if (f32m) {
            float4 x = ((const float4*)src)[i];
            h.x = f2b(x.x); h.y = f2b(x.y); h.z = f2b(x.z); h.w = f2b(x.w);
            l.x = f2b(x.x - b2f(h.x)); l.y = f2b(x.y - b2f(h.y));
            l.z = f2b(x.z - b2f(h.z)); l.w = f2b(x.w - b2f(h.w));
        } else {
            h = ((const ushort4*)src)[i];
            l.x = 0; l.y = 0; l.z = 0; l.w = 0;
        }
        ((ushort4*)dh)[i] = h;
        ((ushort4*)dl)[i] = l;
    }
}

// MwT planes (NEGATED): mwt[c][k] = -(1/n2) * dot(M row k, W_h row c)
__global__ __launch_bounds__(256) void build_mwt_planes(const void* hp,
                                                        const void* Wh,
                                                        void* out,
                                                        u16* mh, u16* ml,
                                                        int which) {
    DETECT_FLAG(hp);
    float* scr = scratch_base(out, f32m);
    const float* M = scr + (size_t)which * 65536;
    const float n2 = scr[131072 + which];
    const float inv = (n2 > 1e-30f) ? 1.0f / n2 : 0.f;
    const int c = blockIdx.x, k = threadIdx.x;
    __shared__ float sw[256];
    sw[k] = ldv(Wh, ((size_t)c << 8) + k, f32m);
    __syncthreads();
    const float4* mp = (const float4*)(M + ((size_t)k << 8));
    float acc = 0.f;
#pragma unroll 8
    for (int j = 0; j < 64; ++j) {
        float4 q = mp[j];
        const float* w = &sw[j * 4];
        acc = fmaf(q.x, w[0], acc);
        acc = fmaf(q.y, w[1], acc);
        acc = fmaf(q.z, w[2], acc);
        acc = fmaf(q.w, w[3], acc);
    }
    const float v = -(inv * acc);
    const u16 h = f2b(v);
    mh[((size_t)c << 8) + k] = h;
    ml[((size_t)c << 8) + k] = f2b(v - b2f(h));
}

// LDS tile layout: [row][8 slots x 16B] = 128B rows; slot = plane*4 + ksub;
// swizzled slot' = slot ^ (row&7)  (2-way bank aliasing only -> free).
__device__ __forceinline__ void stage_tile(u16* dst, const u16* ph, const u16* pl,
                                           int rows, int base, int K0, int t) {
    const int chunks = rows * 8;
#pragma unroll
    for (int c = t; c < chunks; c += 256) {
        const int row = c >> 3, slot = c & 7;
        const u16* src = (slot & 4) ? pl : ph;
        uint4 q = *(const uint4*)(src + (((size_t)(base + row)) << 8) + K0 +
                                  (slot & 3) * 8);
        *(uint4*)(dst + row * 64 + ((slot ^ (row & 7)) << 3)) = q;
    }
}

__device__ __forceinline__ bf16x8 ldfrag(const u16* tile, int row, int pl, int lk) {
    const int slot = pl * 4 + lk;
    return *(const bf16x8*)(tile + row * 64 + ((slot ^ (row & 7)) << 3));
}

__device__ __forceinline__ void mfma_product(const u16* tA, const u16* tB,
                                             int wr, int wc, int lr, int lk,
                                             f32x4 (&acc)[4][2]) {
    bf16x8 ah[4], al[4], bh[2], bl[2];
#pragma unroll
    for (int fr = 0; fr < 4; ++fr) {
        const int r = wr * 64 + fr * 16 + lr;
        ah[fr] = ldfrag(tA, r, 0, lk);
        al[fr] = ldfrag(tA, r, 1, lk);
    }
#pragma unroll
    for (int fc = 0; fc < 2; ++fc) {
        const int c = wc * 32 + fc * 16 + lr;
        bh[fc] = ldfrag(tB, c, 0, lk);
        bl[fc] = ldfrag(tB, c, 1, lk);
    }
#pragma unroll
    for (int fr = 0; fr < 4; ++fr)
#pragma unroll
        for (int fc = 0; fc < 2; ++fc) {
            f32x4 x = acc[fr][fc];
            x = __builtin_amdgcn_mfma_f32_16x16x32_bf16(ah[fr], bh[fc], x, 0, 0, 0);
            x = __builtin_amdgcn_mfma_f32_16x16x32_bf16(ah[fr], bl[fc], x, 0, 0, 0);
            x = __builtin_amdgcn_mfma_f32_16x16x32_bf16(al[fr], bh[fc], x, 0, 0, 0);
            acc[fr][fc] = x;
        }
}

// Block 128 rows x 64 cols; 4 waves (2x2), wave tile 64x32 (4x2 16x16 frags).
// MODE 0 (phaseA): out = tanh(A0@B0^T+b0)+tanh(A1@B1^T+b1); writes Ph/Pl planes.
// MODE 1 (phaseBC): acc1 = A1@B1^T (kc<8) + A0@B2^T (kc>=8, B2 = -MwT planes).
//                   A1 planes and Ph/Pl planes MUST be different slots (race).
// MODE 2 (phaseC2): out_b = tanh(A0@B0^T+b0); N=128; no planes out.
template <int MODE>
__global__ __launch_bounds__(256) void gemm_mfma(
    const void* hp,
    const u16* A0h, const u16* A0l, const u16* A1h, const u16* A1l,
    const u16* B0h, const u16* B0l, const u16* B1h, const u16* B1l,
    const u16* B2h, const u16* B2l,
    const void* bias0, const void* bias1, void* out, u16* Ph, u16* Pl) {
    DETECT_FLAG(hp);

    __shared__ u16 sA0[128 * 64];
    __shared__ u16 sA1[128 * 64];
    __shared__ u16 sB0[64 * 64];
    __shared__ u16 sB1[64 * 64];

    const int t = threadIdx.x;
    const int m0 = blockIdx.x * 128;
    const int n0 = blockIdx.y * 64;
    const int lane = t & 63;
    const int wave = t >> 6;
    const int wr = wave >> 1, wc = wave & 1;
    const int lr = lane & 15, lk = lane >> 4;

    f32x4 acc0[4][2] = {};
    f32x4 acc1[4][2] = {};

    constexpr int NC = (MODE == 1) ? 16 : 8;
#pragma unroll 1
    for (int kc = 0; kc < NC; ++kc) {
        const int K0 = (kc & 7) * 32;
        stage_tile(sA0, A0h, A0l, 128, m0, K0, t);
        if constexpr (MODE != 2) {
            if (kc < 8) stage_tile(sA1, A1h, A1l, 128, m0, K0, t);
        }
        if (kc < 8) stage_tile(sB0, B0h, B0l, 64, n0, K0, t);
        if constexpr (MODE == 0) {
            stage_tile(sB1, B1h, B1l, 64, n0, K0, t);
        } else if constexpr (MODE == 1) {
            if (kc < 8) stage_tile(sB1, B1h, B1l, 64, n0, K0, t);
            else        stage_tile(sB1, B2h, B2l, 64, n0, K0, t);
        }
        __syncthreads();
        if (kc < 8) mfma_product(sA0, sB0, wr, wc, lr, lk, acc0);
        if constexpr (MODE == 0) {
            mfma_product(sA1, sB1, wr, wc, lr, lk, acc1);
        } else if constexpr (MODE == 1) {
            if (kc < 8) mfma_product(sA1, sB1, wr, wc, lr, lk, acc1);
            else        mfma_product(sA0, sB1, wr, wc, lr, lk, acc1);
        }
        __syncthreads();
    }

    // epilogue: C/D map col=lane&15, row=(lane>>4)*4+reg  [m89-verified]
    float b0v[2], b1v[2];
#pragma unroll
    for (int fc = 0; fc < 2; ++fc) {
        const int c = n0 + wc * 32 + fc * 16 + lr;
        b0v[fc] = ldv(bias0, c, f32m);
        if constexpr (MODE != 2) b1v[fc] = ldv(bias1, c, f32m);
    }
#pragma unroll
    for (int fr = 0; fr < 4; ++fr)
#pragma unroll
        for (int j = 0; j < 4; ++j) {
            const size_t r = (size_t)m0 + wr * 64 + fr * 16 + lk * 4 + j;
#pragma unroll
            for (int fc = 0; fc < 2; ++fc) {
                const int c = n0 + wc * 32 + fc * 16 + lr;
                float o = tanhf(acc0[fr][fc][j] + b0v[fc]);
                if constexpr (MODE != 2) o += tanhf(acc1[fr][fc][j] + b1v[fc]);
                if constexpr (MODE == 2) {
                    stv(out, HI_ELEMS + r * BDIM + c, o, f32m);
                } else {
                    stv(out, (r << 8) + c, o, f32m);
                    const u16 h = f2b(o);
                    Ph[(r << 8) + c] = h;
                    Pl[(r << 8) + c] = f32m ? f2b(o - b2f(h)) : (u16)0;
                }
            }
        }
}

extern "C" void kernel_launch(void* const* d_in, const int* in_sizes, int n_in,
                              void* d_out, int out_size, void* d_ws, size_t ws_size,
                              hipStream_t stream) {
    (void)in_sizes; (void)n_in; (void)out_size;
    const void* h_prev = d_in[0];
    const void* n_h  = d_in[1];
    const void* n_r  = d_in[2];
    const void* n_t  = d_in[3];
    const void* W_nh = d_in[4];
    const void* b_nh = d_in[5];
    const void* W_nr = d_in[6];
    const void* b_nr = d_in[7];
    const void* W_nt = d_in[8];
    const void* b_nt = d_in[9];
    const void* W_bt = d_in[10];
    const void* b_bt = d_in[11];
    const void* W_h  = d_in[12];
    const void* b_h  = d_in[13];

    zero_kernel<<<(SCR_FLOATS + 255) / 256, 256, 0, stream>>>(h_prev, d_out);
    norms_kernel<<<2048, 256, 0, stream>>>(h_prev, n_r, n_t, d_out);

    if (ws_size >= (size_t)WS_NEED) {
        char* ws = (char*)d_ws;
        // activation slots: i in {0,1,2}; h plane then l plane
        u16* s0h = (u16*)(ws + 0 * 2 * WSLOT_B);
        u16* s0l = (u16*)(ws + 0 * 2 * WSLOT_B + WSLOT_B);
        u16* s1h = (u16*)(ws + 1 * 2 * WSLOT_B);
        u16* s1l = (u16*)(ws + 1 * 2 * WSLOT_B + WSLOT_B);
        u16* s2h = (u16*)(ws + 2 * 2 * WSLOT_B);
        u16* s2l = (u16*)(ws + 2 * 2 * WSLOT_B + WSLOT_B);
        // weight plane pairs: Wnh(0), Wh(1), Wnr(2), Wnt(3), Wbt(4), MwT(5)
        auto wph = [&](int i) { return (u16*)(ws + WWPL + (size_t)i * 262144); };
        auto wpl = [&](int i) { return (u16*)(ws + WWPL + (size_t)i * 262144 + 131072); };

        split_kernel<<<2048, 256, 0, stream>>>(h_prev, n_h, s0h, s0l, HI_ELEMS);
        split_kernel<<<2048, 256, 0, stream>>>(h_prev, h_prev, s1h, s1l, HI_ELEMS);
        split_kernel<<<64, 256, 0, stream>>>(h_prev, W_nh, wph(0), wpl(0), 65536);
        split_kernel<<<64, 256, 0, stream>>>(h_prev, W_h,  wph(1), wpl(1), 65536);
        split_kernel<<<64, 256, 0, stream>>>(h_prev, W_nr, wph(2), wpl(2), 65536);
        split_kernel<<<64, 256, 0, stream>>>(h_prev, W_nt, wph(3), wpl(3), 65536);
        split_kernel<<<32, 256, 0, stream>>>(h_prev, W_bt, wph(4), wpl(4), 32768);

        // phaseA: reads s0(n_h), s1(h_prev) -> hi planes to s2
        gemm_mfma<0><<<dim3(512, 4), 256, 0, stream>>>(
            h_prev, s0h, s0l, s1h, s1l, wph(0), wpl(0), wph(1), wpl(1),
            nullptr, nullptr, b_nh, b_h, d_out, s2h, s2l);

        // phaseB: reads s0(n_r), s2(hi) -> hi planes to s1  (no read/write overlap)
        colreduce_kernel<<<dim3(4, 64), 512, 0, stream>>>(h_prev, n_r, d_out, 0);
        build_mwt_planes<<<256, 256, 0, stream>>>(h_prev, W_h, d_out, wph(5), wpl(5), 0);
        split_kernel<<<2048, 256, 0, stream>>>(h_prev, n_r, s0h, s0l, HI_ELEMS);
        gemm_mfma<1><<<dim3(512, 4), 256, 0, stream>>>(
            h_prev, s0h, s0l, s2h, s2l, wph(2), wpl(2), wph(1), wpl(1),
            wph(5), wpl(5), b_nr, b_h, d_out, s1h, s1l);

        // phaseC: reads s0(n_t), s1(hi) -> hi planes to s2
        colreduce_kernel<<<dim3(4, 64), 512, 0, stream>>>(h_prev, n_t, d_out, 1);
        build_mwt_planes<<<256, 256, 0, stream>>>(h_prev, W_h, d_out, wph(5), wpl(5), 1);
        split_kernel<<<2048, 256, 0, stream>>>(h_prev, n_t, s0h, s0l, HI_ELEMS);
        gemm_mfma<1><<<dim3(512, 4), 256, 0, stream>>>(
            h_prev, s0h, s0l, s1h, s1l, wph(3), wpl(3), wph(1), wpl(1),
            wph(5), wpl(5), b_nt, b_h, d_out, s2h, s2l);

        // phaseC2: reads s2(h_next)
        gemm_mfma<2><<<dim3(512, 2), 256, 0, stream>>>(
            h_prev, s2h, s2l, nullptr, nullptr, wph(4), wpl(4), nullptr, nullptr,
            nullptr, nullptr, b_bt, nullptr, d_out, nullptr, nullptr);
    } else {
        // fallback: verified f32-VALU path
        gemm_fused<0><<<B_SZ / 32, 256, 0, stream>>>(h_prev, n_h, h_prev, W_nh, W_h,
                                                     b_nh, b_h, d_out);
        colreduce_kernel<<<dim3(4, 64), 512, 0, stream>>>(h_prev, n_r, d_out, 0);
        build_mwt_kernel<<<256, 256, 0, stream>>>(h_prev, W_h, d_out, 0);
        gemm_fused<1><<<B_SZ / 32, 256, 0, stream>>>(h_prev, n_r, d_out, W_nr, W_h,
                                                     b_nr, b_h, d_out);
        colreduce_kernel<<<dim3(4, 64), 512, 0, stream>>>(h_prev, n_t, d_out, 1);
        build_mwt_kernel<<<256, 256, 0, stream>>>(h_prev, W_h, d_out, 1);
        gemm_fused<1><<<B_SZ / 32, 256, 0, stream>>>(h_prev, n_t, d_out, W_nt, W_h,
                                                     b_nt, b_h, d_out);
        gemm_fused<2><<<B_SZ / 32, 128, 0, stream>>>(h_prev, d_out, nullptr, W_bt,
                                                     nullptr, b_bt, nullptr, d_out);
    }
}

// Round 5
// 1383.432 us; speedup vs baseline: 1.5757x; 1.3652x over previous
//
#include <hip/hip_runtime.h>

// B_Cell — B=65536, I=H=256, BD=128. Dtype (bf16 vs f32) detected ON DEVICE.
// R5: replace atomic f32 colreduce (330us, 134MB atomic writes) with an MFMA
// partial-tile reduction GEMM over the existing bf16 hi-planes (no atomics,
// partials in the dead plane slot + small reduceM sum kernel). hi-plane-only
// is numerically safe: M error ~0.35 absolute / n^2=1.7e7 -> ~1e-6 at output.
// Also: wout flag skips dead d_out hi writes in gemm<0> and gemm<1>#1.
// f32-VALU fallback path retained for small ws_size.
//
// d_out scratch (f32, head of b-region):
//   [0,65536) M1 | [65536,131072) M2 | [131072,131074) norms | [131076,...) MwT(f32, fallback only)
// d_ws (MFMA path, ws_size >= WS_NEED):
//   slot0/1/2: activation plane pairs (h,l), each plane 16777216 bf16 = 33.5MB
//   weight plane pairs at WWPL: Wnh, Wh, Wnr, Wnt, Wbt, MwT(negated)
//   colreduce partials (16MB f32) transiently reuse the dead slot's h-plane.

#define B_SZ 65536
#define HDIM 256
#define BDIM 128
#define HI_ELEMS ((size_t)B_SZ * HDIM)       // 16777216
#define SCR_FLOATS (2 * 65536 + 2)
#define MWT_OFF 131076

#define WSLOT_B (2ull * HI_ELEMS)            // bytes per bf16 plane = 33554432
#define WWPL (6ull * WSLOT_B)                // 201326592: weight planes base
#define WS_NEED (WWPL + 6ull * 262144ull)    // 202899456

typedef unsigned short u16;
typedef unsigned int u32;
typedef __attribute__((ext_vector_type(8))) short bf16x8;
typedef __attribute__((ext_vector_type(4))) float f32x4;

__device__ __forceinline__ float blo(u32 u) { return __uint_as_float(u << 16); }
__device__ __forceinline__ float bhi(u32 u) { return __uint_as_float(u & 0xffff0000u); }
__device__ __forceinline__ float b2f(u16 v) { return __uint_as_float(((u32)v) << 16); }
__device__ __forceinline__ u16 f2b(float f) {
    u32 u = __float_as_uint(f);
    return (u16)((u + 0x7fffu + ((u >> 16) & 1u)) >> 16);  // RNE
}

__device__ __forceinline__ int detect_f32_t0(const u16* hp) {
    int sane = 0;
    for (int i = 0; i < 64; ++i) {
        u32 e = (hp[2 * i] >> 7) & 0xFFu;
        sane += (e >= 0x60u && e <= 0x8Fu) ? 1 : 0;
    }
    return (sane < 32) ? 1 : 0;
}

#define DETECT_FLAG(hp)                                                   \
    __shared__ int _sflag;                                                \
    if (threadIdx.x == 0) _sflag = detect_f32_t0((const u16*)(hp));       \
    __syncthreads();                                                      \
    const bool f32m = (_sflag != 0);

__device__ __forceinline__ float ldv(const void* p, size_t i, bool f) {
    return f ? ((const float*)p)[i] : b2f(((const u16*)p)[i]);
}
__device__ __forceinline__ void stv(void* p, size_t i, float v, bool f) {
    if (f) ((float*)p)[i] = v;
    else   ((u16*)p)[i] = f2b(v);
}
__device__ __forceinline__ float* scratch_base(void* out, bool f) {
    return (float*)((char*)out + HI_ELEMS * (f ? 4u : 2u));
}
__device__ __forceinline__ void stv4(void* p, size_t i, const float* v, bool f) {
    if (f) {
        *(float4*)((float*)p + i) = make_float4(v[0], v[1], v[2], v[3]);
    } else {
        ushort4 s;
        s.x = f2b(v[0]); s.y = f2b(v[1]); s.z = f2b(v[2]); s.w = f2b(v[3]);
        *(ushort4*)((u16*)p + i) = s;
    }
}

__global__ __launch_bounds__(256) void zero_kernel(const void* hp, void* out) {
    DETECT_FLAG(hp);
    float* scr = scratch_base(out, f32m);
    const int idx = blockIdx.x * 256 + threadIdx.x;
    if (idx < SCR_FLOATS) scr[idx] = 0.f;
}

__global__ __launch_bounds__(256) void norms_kernel(const void* hp,
                                                    const void* nr,
                                                    const void* nt,
                                                    void* out) {
    DETECT_FLAG(hp);
    float* scr = scratch_base(out, f32m);
    const size_t total4 = HI_ELEMS / 4;
    const size_t stride = (size_t)gridDim.x * blockDim.x;
    float sr = 0.f, st = 0.f;
    for (size_t i = (size_t)blockIdx.x * blockDim.x + threadIdx.x; i < total4;
         i += stride) {
        if (f32m) {
            float4 a = ((const float4*)nr)[i];
            float4 b = ((const float4*)nt)[i];
            sr = fmaf(a.x, a.x, sr); sr = fmaf(a.y, a.y, sr);
            sr = fmaf(a.z, a.z, sr); sr = fmaf(a.w, a.w, sr);
            st = fmaf(b.x, b.x, st); st = fmaf(b.y, b.y, st);
            st = fmaf(b.z, b.z, st); st = fmaf(b.w, b.w, st);
        } else {
            uint2 a = ((const uint2*)nr)[i];
            uint2 b = ((const uint2*)nt)[i];
            float a0 = blo(a.x), a1 = bhi(a.x), a2 = blo(a.y), a3 = bhi(a.y);
            float b0 = blo(b.x), b1 = bhi(b.x), b2 = blo(b.y), b3 = bhi(b.y);
            sr = fmaf(a0, a0, sr); sr = fmaf(a1, a1, sr);
            sr = fmaf(a2, a2, sr); sr = fmaf(a3, a3, sr);
            st = fmaf(b0, b0, st); st = fmaf(b1, b1, st);
            st = fmaf(b2, b2, st); st = fmaf(b3, b3, st);
        }
    }
    for (int o = 32; o > 0; o >>= 1) {
        sr += __shfl_down(sr, o);
        st += __shfl_down(st, o);
    }
    if ((threadIdx.x & 63) == 0) {
        atomicAdd(&scr[131072], sr);
        atomicAdd(&scr[131073], st);
    }
}

// ---------- fallback f32 colreduce (atomic version) ----------
__global__ __launch_bounds__(512) void colreduce_kernel(const void* hp,
                                                        const void* A,
                                                        void* out, int which) {
    DETECT_FLAG(hp);
    float* M = scratch_base(out, f32m) + (size_t)which * 65536;
    const int k0 = (blockIdx.x >> 1) * 128;
    const int c0 = (blockIdx.x & 1) * 128;
    const size_t r0 = (size_t)blockIdx.y * 1024;
    const int t = threadIdx.x;
    const int tk = t >> 4;
    const int tc = t & 15;

    __shared__ float vS[16][132];
    __shared__ float hS[16][132];

    const int rr = t >> 5;
    const int sg = t & 31;
    const bool isv = sg < 16;
    const int cw = (isv ? sg : sg - 16) * 8;
    const void* src = isv ? A : (const void*)out;
    const int cg = (isv ? k0 : c0) + cw;
    float* dst = isv ? &vS[rr][cw] : &hS[rr][cw];

    float acc[4][8] = {};
#pragma unroll 1
    for (int rc = 0; rc < 64; ++rc) {
        const size_t r = r0 + (size_t)rc * 16 + rr;
        if (f32m) {
            const float4* p = (const float4*)((const float*)src + (r << 8) + cg);
            float4 q0 = p[0], q1 = p[1];
            dst[0] = q0.x; dst[1] = q0.y; dst[2] = q0.z; dst[3] = q0.w;
            dst[4] = q1.x; dst[5] = q1.y; dst[6] = q1.z; dst[7] = q1.w;
        } else {
            const uint4* p = (const uint4*)((const u16*)src + (r << 8) + cg);
            uint4 q = p[0];
            dst[0] = blo(q.x); dst[1] = bhi(q.x);
            dst[2] = blo(q.y); dst[3] = bhi(q.y);
            dst[4] = blo(q.z); dst[5] = bhi(q.z);
            dst[6] = blo(q.w); dst[7] = bhi(q.w);
        }
        __syncthreads();
#pragma unroll
        for (int j = 0; j < 16; ++j) {
            float4 aq = *(const float4*)&vS[j][tk * 4];
            float4 b0 = *(const float4*)&hS[j][tc * 8];
            float4 b1 = *(const float4*)&hS[j][tc * 8 + 4];
            float a[4] = {aq.x, aq.y, aq.z, aq.w};
            float b[8] = {b0.x, b0.y, b0.z, b0.w, b1.x, b1.y, b1.z, b1.w};
#pragma unroll
            for (int i = 0; i < 4; ++i)
#pragma unroll
                for (int jj = 0; jj < 8; ++jj)
                    acc[i][jj] = fmaf(a[i], b[jj], acc[i][jj]);
        }
        __syncthreads();
    }
#pragma unroll
    for (int i = 0; i < 4; ++i)
#pragma unroll
        for (int j = 0; j < 8; ++j)
            atomicAdd(&M[(size_t)(k0 + tk * 4 + i) * 256 + (c0 + tc * 8 + j)],
                      acc[i][j]);
}

// ---------- fallback (f32 VALU) path: build_mwt + gemm_fused ----------

__global__ __launch_bounds__(256) void build_mwt_kernel(const void* hp,
                                                        const void* Wh,
                                                        void* out, int which) {
    DETECT_FLAG(hp);
    float* scr = scratch_base(out, f32m);
    const float* M = scr + (size_t)which * 65536;
    const float n2 = scr[131072 + which];
    const float inv = (n2 > 1e-30f) ? 1.0f / n2 : 0.f;
    float* MwT = scr + MWT_OFF;
    const int c = blockIdx.x, k = threadIdx.x;
    __shared__ float sw[256];
    sw[k] = ldv(Wh, ((size_t)c << 8) + k, f32m);
    __syncthreads();
    const float4* mp = (const float4*)(M + ((size_t)k << 8));
    float acc = 0.f;
#pragma unroll 8
    for (int j = 0; j < 64; ++j) {
        float4 q = mp[j];
        const float* w = &sw[j * 4];
        acc = fmaf(q.x, w[0], acc);
        acc = fmaf(q.y, w[1], acc);
        acc = fmaf(q.z, w[2], acc);
        acc = fmaf(q.w, w[3], acc);
    }
    MwT[((size_t)c << 8) + k] = inv * acc;
}

template <int MODE>
__global__ __launch_bounds__((MODE == 2) ? 128 : 256) void gemm_fused(
    const void* hp, const void* A0p, const void* A1p, const void* B0p,
    const void* B1p, const void* bias0, const void* bias1, void* out) {
    constexpr int NA = (MODE == 2) ? 1 : 2;
    constexpr int NB = (MODE == 0) ? 2 : ((MODE == 1) ? 3 : 1);
    constexpr int BN = (MODE == 2) ? 128 : 256;
    constexpr int TX = BN / 4;

    DETECT_FLAG(hp);
    const float* MwT =
        (MODE == 1) ? (scratch_base(out, f32m) + MWT_OFF) : (const float*)nullptr;

    __shared__ float As[NA][16][36];
    __shared__ float Bs[NB][16][BN];

    const int t = threadIdx.x;
    const int tx = t % TX;
    const int ty = t / TX;
    const int m0 = blockIdx.x * 32;

    const int sm = t & 31;
    const int sgp = t >> 5;
    const int smat = sgp >> 2;
    const int sk4 = (sgp & 3) * 4;

    float acc[NB][8][4] = {};

#pragma unroll 1
    for (int kc = 0; kc < 16; ++kc) {
        const int k0 = kc * 16;
        {
            const int n = t;
#pragma unroll
            for (int b = 0; b < NB; ++b) {
                const void* W = (b == 0) ? B0p : ((b == 1) ? B1p : (const void*)MwT);
                const bool bf32 = f32m || (b == 2);
                float* d = &Bs[b][0][n];
                if (bf32) {
                    const float4* p =
                        (const float4*)((const float*)W + ((size_t)n << 8) + k0);
                    float4 q0 = p[0], q1 = p[1], q2 = p[2], q3 = p[3];
                    d[0 * BN] = q0.x; d[1 * BN] = q0.y; d[2 * BN] = q0.z; d[3 * BN] = q0.w;
                    d[4 * BN] = q1.x; d[5 * BN] = q1.y; d[6 * BN] = q1.z; d[7 * BN] = q1.w;
                    d[8 * BN] = q2.x; d[9 * BN] = q2.y; d[10 * BN] = q2.z; d[11 * BN] = q2.w;
                    d[12 * BN] = q3.x; d[13 * BN] = q3.y; d[14 * BN] = q3.z; d[15 * BN] = q3.w;
                } else {
                    const uint4* p =
                        (const uint4*)((const u16*)W + ((size_t)n << 8) + k0);
                    uint4 q0 = p[0], q1 = p[1];
                    d[0 * BN] = blo(q0.x); d[1 * BN] = bhi(q0.x);
                    d[2 * BN] = blo(q0.y); d[3 * BN] = bhi(q0.y);
                    d[4 * BN] = blo(q0.z); d[5 * BN] = bhi(q0.z);
                    d[6 * BN] = blo(q0.w); d[7 * BN] = bhi(q0.w);
                    d[8 * BN] = blo(q1.x); d[9 * BN] = bhi(q1.x);
                    d[10 * BN] = blo(q1.y); d[11 * BN] = bhi(q1.y);
                    d[12 * BN] = blo(q1.z); d[13 * BN] = bhi(q1.z);
                    d[14 * BN] = blo(q1.w); d[15 * BN] = bhi(q1.w);
                }
            }
        }
        {
            const void* A = (smat == 0) ? A0p : A1p;
            const size_t off = ((size_t)(m0 + sm) << 8) + k0 + sk4;
            if (f32m) {
                float4 q = *(const float4*)((const float*)A + off);
                As[smat][sk4 + 0][sm] = q.x;
                As[smat][sk4 + 1][sm] = q.y;
                As[smat][sk4 + 2][sm] = q.z;
                As[smat][sk4 + 3][sm] = q.w;
            } else {
                const u32* p = (const u32*)((const u16*)A + off);
                u32 q0 = p[0], q1 = p[1];
                As[smat][sk4 + 0][sm] = blo(q0);
                As[smat][sk4 + 1][sm] = bhi(q0);
                As[smat][sk4 + 2][sm] = blo(q1);
                As[smat][sk4 + 3][sm] = bhi(q1);
            }
        }
        __syncthreads();
#pragma unroll
        for (int k = 0; k < 16; ++k) {
            float a0[8], a1[8];
            {
                float4 u = *(const float4*)&As[0][k][ty * 8];
                float4 v = *(const float4*)&As[0][k][ty * 8 + 4];
                a0[0] = u.x; a0[1] = u.y; a0[2] = u.z; a0[3] = u.w;
                a0[4] = v.x; a0[5] = v.y; a0[6] = v.z; a0[7] = v.w;
            }
            if constexpr (NA == 2) {
                float4 u = *(const float4*)&As[1][k][ty * 8];
                float4 v = *(const float4*)&As[1][k][ty * 8 + 4];
                a1[0] = u.x; a1[1] = u.y; a1[2] = u.z; a1[3] = u.w;
                a1[4] = v.x; a1[5] = v.y; a1[6] = v.z; a1[7] = v.w;
            }
            float b0[4], b1[4], b2[4];
            {
                float4 u = *(const float4*)&Bs[0][k][tx * 4];
                b0[0] = u.x; b0[1] = u.y; b0[2] = u.z; b0[3] = u.w;
            }
            if constexpr (NB >= 2) {
                float4 u = *(const float4*)&Bs[1][k][tx * 4];
                b1[0] = u.x; b1[1] = u.y; b1[2] = u.z; b1[3] = u.w;
            }
            if constexpr (NB == 3) {
                float4 u = *(const float4*)&Bs[2][k][tx * 4];
                b2[0] = u.x; b2[1] = u.y; b2[2] = u.z; b2[3] = u.w;
            }
#pragma unroll
            for (int i = 0; i < 8; ++i)
#pragma unroll
                for (int j = 0; j < 4; ++j) {
                    acc[0][i][j] = fmaf(a0[i], b0[j], acc[0][i][j]);
                    if constexpr (NB >= 2)
                        acc[1][i][j] = fmaf(a1[i], b1[j], acc[1][i][j]);
                    if constexpr (NB == 3)
                        acc[2][i][j] = fmaf(a0[i], b2[j], acc[2][i][j]);
                }
        }
        __syncthreads();
    }

    float b0v[4], b1v[4];
#pragma unroll
    for (int j = 0; j < 4; ++j) {
        b0v[j] = ldv(bias0, tx * 4 + j, f32m);
        if constexpr (MODE != 2) b1v[j] = ldv(bias1, tx * 4 + j, f32m);
    }
#pragma unroll
    for (int i = 0; i < 8; ++i) {
        const size_t r = (size_t)m0 + ty * 8 + i;
        float vo[4];
#pragma unroll
        for (int j = 0; j < 4; ++j) {
            if constexpr (MODE == 0)
                vo[j] = tanhf(acc[0][i][j] + b0v[j]) + tanhf(acc[1][i][j] + b1v[j]);
            else if constexpr (MODE == 1)
                vo[j] = tanhf(acc[0][i][j] + b0v[j]) +
                        tanhf(acc[1][i][j] - acc[2][i][j] + b1v[j]);
            else
                vo[j] = tanhf(acc[0][i][j] + b0v[j]);
        }
        if constexpr (MODE == 2)
            stv4(out, HI_ELEMS + r * BDIM + tx * 4, vo, f32m);
        else
            stv4(out, (r << 8) + tx * 4, vo, f32m);
    }
}

// ---------- MFMA (bf16x3) path ----------

__global__ __launch_bounds__(256) void split_kernel(const void* hp,
                                                    const void* src,
                                                    u16* dh, u16* dl, size_t n) {
    DETECT_FLAG(hp);
    const size_t n4 = n / 4;
    const size_t stride = (size_t)gridDim.x * blockDim.x;
    for (size_t i = (size_t)blockIdx.x * blockDim.x + threadIdx.x; i < n4;
         i += stride) {
        ushort4 h, l;
        if (f32m) {
            float4 x = ((const float4*)src)[i];
            h.x = f2b(x.x); h.y = f2b(x.y); h.z = f2b(x.z); h.w = f2b(x.w);
            l.x = f2b(x.x - b2f(h.x)); l.y = f2b(x.y - b2f(h.y));
            l.z = f2b(x.z - b2f(h.z)); l.w = f2b(x.w - b2f(h.w));
        } else {
            h = ((const ushort4*)src)[i];
            l.x = 0; l.y = 0; l.z = 0; l.w = 0;
        }
        ((ushort4*)dh)[i] = h;
        ((ushort4*)dl)[i] = l;
    }
}

// MwT planes (NEGATED): mwt[c][k] = -(1/n2) * dot(M row k, W_h row c)
__global__ __launch_bounds__(256) void build_mwt_planes(const void* hp,
                                                        const void* Wh,
                                                        void* out,
                                                        u16* mh, u16* ml,
                                                        int which) {
    DETECT_FLAG(hp);
    float* scr = scratch_base(out, f32m);
    const float* M = scr + (size_t)which * 65536;
    const float n2 = scr[131072 + which];
    const float inv = (n2 > 1e-30f) ? 1.0f / n2 : 0.f;
    const int c = blockIdx.x, k = threadIdx.x;
    __shared__ float sw[256];
    sw[k] = ldv(Wh, ((size_t)c << 8) + k, f32m);
    __syncthreads();
    const float4* mp = (const float4*)(M + ((size_t)k << 8));
    float acc = 0.f;
#pragma unroll 8
    for (int j = 0; j < 64; ++j) {
        float4 q = mp[j];
        const float* w = &sw[j * 4];
        acc = fmaf(q.x, w[0], acc);
        acc = fmaf(q.y, w[1], acc);
        acc = fmaf(q.z, w[2], acc);
        acc = fmaf(q.w, w[3], acc);
    }
    const float v = -(inv * acc);
    const u16 h = f2b(v);
    mh[((size_t)c << 8) + k] = h;
    ml[((size_t)c << 8) + k] = f2b(v - b2f(h));
}

// M-partials via MFMA over hi planes only. Output tile 128(k)x128(c); 4 waves
// (2x2), wave-tile 64x64 (4x4 16x16 frags). grid = dim3(4, 64):
// x -> (ktile, ctile), y -> r-chunk of 1024 rows. No atomics: each block
// writes its own 128x128 quadrant of partial P[by][256][256].
// LDS tiles [row][64 r] (128B rows), slot-XOR swizzle as in gemm_mfma.
__global__ __launch_bounds__(256) void colreduce_mfma(
    const u16* __restrict__ Vh, const u16* __restrict__ Hh,
    float* __restrict__ P) {
    const int kt = blockIdx.x >> 1, ct = blockIdx.x & 1;
    const size_t r0 = (size_t)blockIdx.y * 1024;

    __shared__ u16 tA[128 * 64];   // [kout][r] (transposed v)
    __shared__ u16 tB[128 * 64];   // [c][r]    (transposed hi)

    const int t = threadIdx.x;
    const int lane = t & 63, wave = t >> 6;
    const int wr = wave >> 1, wc = wave & 1;
    const int lr = lane & 15, lk = lane >> 4;
    const int sr = t & 63;         // staging row-in-chunk (lane id)
    const int w0 = t >> 6;

    f32x4 acc[4][4] = {};

#pragma unroll 1
    for (int rc = 0; rc < 16; ++rc) {
        const size_t rb = r0 + (size_t)rc * 64;
        // stage A: tA[kout][r] = Vh[rb+r][kt*128+kout]; lane-per-row loads,
        // 8x ds_write_b16 each (64 lanes cover all 32 banks, 2-way = free)
#pragma unroll
        for (int p = 0; p < 4; ++p) {
            const int kq = w0 + 4 * p;  // 0..15
            uint4 q = *(const uint4*)(Vh + (rb + sr) * 256 + kt * 128 + kq * 8);
            const u16* qv = (const u16*)&q;
#pragma unroll
            for (int i = 0; i < 8; ++i) {
                const int row = kq * 8 + i;
                tA[row * 64 + (((sr >> 3) ^ (row & 7)) << 3) + (sr & 7)] = qv[i];
            }
        }
        // stage B: tB[c][r] = Hh[rb+r][ct*128+c]
#pragma unroll
        for (int p = 0; p < 4; ++p) {
            const int kq = w0 + 4 * p;
            uint4 q = *(const uint4*)(Hh + (rb + sr) * 256 + ct * 128 + kq * 8);
            const u16* qv = (const u16*)&q;
#pragma unroll
            for (int i = 0; i < 8; ++i) {
                const int row = kq * 8 + i;
                tB[row * 64 + (((sr >> 3) ^ (row & 7)) << 3) + (sr & 7)] = qv[i];
            }
        }
        __syncthreads();
#pragma unroll
        for (int ks = 0; ks < 2; ++ks) {
            bf16x8 af[4], bf[4];
#pragma unroll
            for (int fr = 0; fr < 4; ++fr) {
                const int row = wr * 64 + fr * 16 + lr;
                const int slot = (ks * 4 + lk) ^ (row & 7);
                af[fr] = *(const bf16x8*)(tA + row * 64 + slot * 8);
            }
#pragma unroll
            for (int fc = 0; fc < 4; ++fc) {
                const int row = wc * 64 + fc * 16 + lr;
                const int slot = (ks * 4 + lk) ^ (row & 7);
                bf[fc] = *(const bf16x8*)(tB + row * 64 + slot * 8);
            }
#pragma unroll
            for (int fr = 0; fr < 4; ++fr)
#pragma unroll
                for (int fc = 0; fc < 4; ++fc)
                    acc[fr][fc] = __builtin_amdgcn_mfma_f32_16x16x32_bf16(
                        af[fr], bf[fc], acc[fr][fc], 0, 0, 0);
        }
        __syncthreads();
    }

    // write partial tile: P[by][k][c]; C/D map col=lane&15, row=lk*4+reg
    float* Pb = P + (size_t)blockIdx.y * 65536;
#pragma unroll
    for (int fr = 0; fr < 4; ++fr)
#pragma unroll
        for (int j = 0; j < 4; ++j) {
            const int k = kt * 128 + wr * 64 + fr * 16 + lk * 4 + j;
#pragma unroll
            for (int fc = 0; fc < 4; ++fc) {
                const int c = ct * 128 + wc * 64 + fc * 16 + lr;
                Pb[k * 256 + c] = acc[fr][fc][j];
            }
        }
}

// M{which}[k][c] = sum_p P[p][k][c]  (64 partials)
__global__ __launch_bounds__(256) void reduceM_kernel(const void* hp,
                                                      const float* __restrict__ P,
                                                      void* out, int which) {
    DETECT_FLAG(hp);
    float* M = scratch_base(out, f32m) + (size_t)which * 65536;
    const int idx = blockIdx.x * 256 + threadIdx.x;
    float s = 0.f;
#pragma unroll 8
    for (int p = 0; p < 64; ++p) s += P[(size_t)p * 65536 + idx];
    M[idx] = s;
}

// LDS tile layout: [row][8 slots x 16B] = 128B rows; slot = plane*4 + ksub;
// swizzled slot' = slot ^ (row&7).
__device__ __forceinline__ void stage_tile(u16* dst, const u16* ph, const u16* pl,
                                           int rows, int base, int K0, int t) {
    const int chunks = rows * 8;
#pragma unroll
    for (int c = t; c < chunks; c += 256) {
        const int row = c >> 3, slot = c & 7;
        const u16* src = (slot & 4) ? pl : ph;
        uint4 q = *(const uint4*)(src + (((size_t)(base + row)) << 8) + K0 +
                                  (slot & 3) * 8);
        *(uint4*)(dst + row * 64 + ((slot ^ (row & 7)) << 3)) = q;
    }
}

__device__ __forceinline__ bf16x8 ldfrag(const u16* tile, int row, int pl, int lk) {
    const int slot = pl * 4 + lk;
    return *(const bf16x8*)(tile + row * 64 + ((slot ^ (row & 7)) << 3));
}

__device__ __forceinline__ void mfma_product(const u16* tA, const u16* tB,
                                             int wr, int wc, int lr, int lk,
                                             f32x4 (&acc)[4][2]) {
    bf16x8 ah[4], al[4], bh[2], bl[2];
#pragma unroll
    for (int fr = 0; fr < 4; ++fr) {
        const int r = wr * 64 + fr * 16 + lr;
        ah[fr] = ldfrag(tA, r, 0, lk);
        al[fr] = ldfrag(tA, r, 1, lk);
    }
#pragma unroll
    for (int fc = 0; fc < 2; ++fc) {
        const int c = wc * 32 + fc * 16 + lr;
        bh[fc] = ldfrag(tB, c, 0, lk);
        bl[fc] = ldfrag(tB, c, 1, lk);
    }
#pragma unroll
    for (int fr = 0; fr < 4; ++fr)
#pragma unroll
        for (int fc = 0; fc < 2; ++fc) {
            f32x4 x = acc[fr][fc];
            x = __builtin_amdgcn_mfma_f32_16x16x32_bf16(ah[fr], bh[fc], x, 0, 0, 0);
            x = __builtin_amdgcn_mfma_f32_16x16x32_bf16(ah[fr], bl[fc], x, 0, 0, 0);
            x = __builtin_amdgcn_mfma_f32_16x16x32_bf16(al[fr], bh[fc], x, 0, 0, 0);
            acc[fr][fc] = x;
        }
}

// Block 128 rows x 64 cols; 4 waves (2x2), wave tile 64x32 (4x2 16x16 frags).
// MODE 0 (phaseA): out = tanh(A0@B0^T+b0)+tanh(A1@B1^T+b1); writes Ph/Pl planes.
// MODE 1 (phaseBC): acc1 = A1@B1^T (kc<8) + A0@B2^T (kc>=8, B2 = -MwT planes).
//                   A1 planes and Ph/Pl planes MUST be different slots (race).
// MODE 2 (phaseC2): out_b = tanh(A0@B0^T+b0); N=128; no planes out.
// wout: write the f32/bf16 result to d_out hi region (only needed for phaseC).
template <int MODE>
__global__ __launch_bounds__(256) void gemm_mfma(
    const void* hp,
    const u16* A0h, const u16* A0l, const u16* A1h, const u16* A1l,
    const u16* B0h, const u16* B0l, const u16* B1h, const u16* B1l,
    const u16* B2h, const u16* B2l,
    const void* bias0, const void* bias1, void* out, u16* Ph, u16* Pl,
    int wout) {
    DETECT_FLAG(hp);

    __shared__ u16 sA0[128 * 64];
    __shared__ u16 sA1[128 * 64];
    __shared__ u16 sB0[64 * 64];
    __shared__ u16 sB1[64 * 64];

    const int t = threadIdx.x;
    const int m0 = blockIdx.x * 128;
    const int n0 = blockIdx.y * 64;
    const int lane = t & 63;
    const int wave = t >> 6;
    const int wr = wave >> 1, wc = wave & 1;
    const int lr = lane & 15, lk = lane >> 4;

    f32x4 acc0[4][2] = {};
    f32x4 acc1[4][2] = {};

    constexpr int NC = (MODE == 1) ? 16 : 8;
#pragma unroll 1
    for (int kc = 0; kc < NC; ++kc) {
        const int K0 = (kc & 7) * 32;
        stage_tile(sA0, A0h, A0l, 128, m0, K0, t);
        if constexpr (MODE != 2) {
            if (kc < 8) stage_tile(sA1, A1h, A1l, 128, m0, K0, t);
        }
        if (kc < 8) stage_tile(sB0, B0h, B0l, 64, n0, K0, t);
        if constexpr (MODE == 0) {
            stage_tile(sB1, B1h, B1l, 64, n0, K0, t);
        } else if constexpr (MODE == 1) {
            if (kc < 8) stage_tile(sB1, B1h, B1l, 64, n0, K0, t);
            else        stage_tile(sB1, B2h, B2l, 64, n0, K0, t);
        }
        __syncthreads();
        if (kc < 8) mfma_product(sA0, sB0, wr, wc, lr, lk, acc0);
        if constexpr (MODE == 0) {
            mfma_product(sA1, sB1, wr, wc, lr, lk, acc1);
        } else if constexpr (MODE == 1) {
            if (kc < 8) mfma_product(sA1, sB1, wr, wc, lr, lk, acc1);
            else        mfma_product(sA0, sB1, wr, wc, lr, lk, acc1);
        }
        __syncthreads();
    }

    // epilogue: C/D map col=lane&15, row=(lane>>4)*4+reg  [m89-verified]
    float b0v[2], b1v[2];
#pragma unroll
    for (int fc = 0; fc < 2; ++fc) {
        const int c = n0 + wc * 32 + fc * 16 + lr;
        b0v[fc] = ldv(bias0, c, f32m);
        if constexpr (MODE != 2) b1v[fc] = ldv(bias1, c, f32m);
    }
#pragma unroll
    for (int fr = 0; fr < 4; ++fr)
#pragma unroll
        for (int j = 0; j < 4; ++j) {
            const size_t r = (size_t)m0 + wr * 64 + fr * 16 + lk * 4 + j;
#pragma unroll
            for (int fc = 0; fc < 2; ++fc) {
                const int c = n0 + wc * 32 + fc * 16 + lr;
                float o = tanhf(acc0[fr][fc][j] + b0v[fc]);
                if constexpr (MODE != 2) o += tanhf(acc1[fr][fc][j] + b1v[fc]);
                if constexpr (MODE == 2) {
                    stv(out, HI_ELEMS + r * BDIM + c, o, f32m);
                } else {
                    if (wout) stv(out, (r << 8) + c, o, f32m);
                    const u16 h = f2b(o);
                    Ph[(r << 8) + c] = h;
                    Pl[(r << 8) + c] = f32m ? f2b(o - b2f(h)) : (u16)0;
                }
            }
        }
}

extern "C" void kernel_launch(void* const* d_in, const int* in_sizes, int n_in,
                              void* d_out, int out_size, void* d_ws, size_t ws_size,
                              hipStream_t stream) {
    (void)in_sizes; (void)n_in; (void)out_size;
    const void* h_prev = d_in[0];
    const void* n_h  = d_in[1];
    const void* n_r  = d_in[2];
    const void* n_t  = d_in[3];
    const void* W_nh = d_in[4];
    const void* b_nh = d_in[5];
    const void* W_nr = d_in[6];
    const void* b_nr = d_in[7];
    const void* W_nt = d_in[8];
    const void* b_nt = d_in[9];
    const void* W_bt = d_in[10];
    const void* b_bt = d_in[11];
    const void* W_h  = d_in[12];
    const void* b_h  = d_in[13];

    zero_kernel<<<(SCR_FLOATS + 255) / 256, 256, 0, stream>>>(h_prev, d_out);
    norms_kernel<<<2048, 256, 0, stream>>>(h_prev, n_r, n_t, d_out);

    if (ws_size >= (size_t)WS_NEED) {
        char* ws = (char*)d_ws;
        u16* s0h = (u16*)(ws + 0 * 2 * WSLOT_B);
        u16* s0l = (u16*)(ws + 0 * 2 * WSLOT_B + WSLOT_B);
        u16* s1h = (u16*)(ws + 1 * 2 * WSLOT_B);
        u16* s1l = (u16*)(ws + 1 * 2 * WSLOT_B + WSLOT_B);
        u16* s2h = (u16*)(ws + 2 * 2 * WSLOT_B);
        u16* s2l = (u16*)(ws + 2 * 2 * WSLOT_B + WSLOT_B);
        auto wph = [&](int i) { return (u16*)(ws + WWPL + (size_t)i * 262144); };
        auto wpl = [&](int i) { return (u16*)(ws + WWPL + (size_t)i * 262144 + 131072); };

        split_kernel<<<2048, 256, 0, stream>>>(h_prev, n_h, s0h, s0l, HI_ELEMS);
        split_kernel<<<2048, 256, 0, stream>>>(h_prev, h_prev, s1h, s1l, HI_ELEMS);
        split_kernel<<<64, 256, 0, stream>>>(h_prev, W_nh, wph(0), wpl(0), 65536);
        split_kernel<<<64, 256, 0, stream>>>(h_prev, W_h,  wph(1), wpl(1), 65536);
        split_kernel<<<64, 256, 0, stream>>>(h_prev, W_nr, wph(2), wpl(2), 65536);
        split_kernel<<<64, 256, 0, stream>>>(h_prev, W_nt, wph(3), wpl(3), 65536);
        split_kernel<<<32, 256, 0, stream>>>(h_prev, W_bt, wph(4), wpl(4), 32768);

        // phaseA: reads s0(n_h), s1(h_prev) -> hi planes to s2 (no d_out write)
        gemm_mfma<0><<<dim3(512, 4), 256, 0, stream>>>(
            h_prev, s0h, s0l, s1h, s1l, wph(0), wpl(0), wph(1), wpl(1),
            nullptr, nullptr, b_nh, b_h, d_out, s2h, s2l, 0);

        // phaseB: M1 = n_r^T @ hi via MFMA partials (partials in dead s1h)
        split_kernel<<<2048, 256, 0, stream>>>(h_prev, n_r, s0h, s0l, HI_ELEMS);
        colreduce_mfma<<<dim3(4, 64), 256, 0, stream>>>(s0h, s2h, (float*)s1h);
        reduceM_kernel<<<256, 256, 0, stream>>>(h_prev, (const float*)s1h, d_out, 0);
        build_mwt_planes<<<256, 256, 0, stream>>>(h_prev, W_h, d_out, wph(5), wpl(5), 0);
        gemm_mfma<1><<<dim3(512, 4), 256, 0, stream>>>(
            h_prev, s0h, s0l, s2h, s2l, wph(2), wpl(2), wph(1), wpl(1),
            wph(5), wpl(5), b_nr, b_h, d_out, s1h, s1l, 0);

        // phaseC: M2 = n_t^T @ hi1 via MFMA partials (partials in dead s2h)
        split_kernel<<<2048, 256, 0, stream>>>(h_prev, n_t, s0h, s0l, HI_ELEMS);
        colreduce_mfma<<<dim3(4, 64), 256, 0, stream>>>(s0h, s1h, (float*)s2h);
        reduceM_kernel<<<256, 256, 0, stream>>>(h_prev, (const float*)s2h, d_out, 1);
        build_mwt_planes<<<256, 256, 0, stream>>>(h_prev, W_h, d_out, wph(5), wpl(5), 1);
        gemm_mfma<1><<<dim3(512, 4), 256, 0, stream>>>(
            h_prev, s0h, s0l, s1h, s1l, wph(3), wpl(3), wph(1), wpl(1),
            wph(5), wpl(5), b_nt, b_h, d_out, s2h, s2l, 1);

        // phaseC2: reads s2(h_next)
        gemm_mfma<2><<<dim3(512, 2), 256, 0, stream>>>(
            h_prev, s2h, s2l, nullptr, nullptr, wph(4), wpl(4), nullptr, nullptr,
            nullptr, nullptr, b_bt, nullptr, d_out, nullptr, nullptr, 1);
    } else {
        // fallback: verified f32-VALU path
        gemm_fused<0><<<B_SZ / 32, 256, 0, stream>>>(h_prev, n_h, h_prev, W_nh, W_h,
                                                     b_nh, b_h, d_out);
        colreduce_kernel<<<dim3(4, 64), 512, 0, stream>>>(h_prev, n_r, d_out, 0);
        build_mwt_kernel<<<256, 256, 0, stream>>>(h_prev, W_h, d_out, 0);
        gemm_fused<1><<<B_SZ / 32, 256, 0, stream>>>(h_prev, n_r, d_out, W_nr, W_h,
                                                     b_nr, b_h, d_out);
        colreduce_kernel<<<dim3(4, 64), 512, 0, stream>>>(h_prev, n_t, d_out, 1);
        build_mwt_kernel<<<256, 256, 0, stream>>>(h_prev, W_h, d_out, 1);
        gemm_fused<1><<<B_SZ / 32, 256, 0, stream>>>(h_prev, n_t, d_out, W_nt, W_h,
                                                     b_nt, b_h, d_out);
        gemm_fused<2><<<B_SZ / 32, 128, 0, stream>>>(h_prev, d_out, nullptr, W_bt,
                                                     nullptr, b_bt, nullptr, d_out);
    }
}